// Round 15
// baseline (54.590 us; speedup 1.0000x reference)
//
#include <hip/hip_runtime.h>
#include <hip/hip_bf16.h>
#include <hip/hip_fp16.h>

typedef __attribute__((ext_vector_type(8))) short bf16x8;
typedef __attribute__((ext_vector_type(4))) float f32x4;
typedef __attribute__((ext_vector_type(4))) int   i32x4;

#define O_TOTAL 8192
#define I_TOTAL 8192
#define ROW_I32 4096       // int32 per weight row
#define NBLOCKS 256        // 32-wide k-blocks per row
#define OUT_N   (16 * O_TOTAL)

typedef __attribute__((address_space(1))) const void GASV;
typedef __attribute__((address_space(3))) void LASV;

static __device__ __forceinline__ short f2bf(float f) {
    union { __hip_bfloat16 b; short s; } u;
    u.b = __float2bfloat16(f);
    return u.s;
}

static __device__ __forceinline__ float bf2f(unsigned short s) {
    union { unsigned int u; float f; } v;
    v.u = ((unsigned int)s) << 16;
    return v.f;
}

static __device__ __forceinline__ int sniff_fmt(const void* wn) {
    const unsigned int* w32 = (const unsigned int*)wn;
    int cntLo = 0, cntHi = 0;
    #pragma unroll
    for (int i = 0; i < 16; ++i) {
        unsigned int ww = w32[i];
        unsigned int lo = ww & 0xFFFFu, hi = ww >> 16;
        if (lo >= 0x3980u && lo < 0x3F80u) cntLo++;
        if (hi >= 0x3C00u) cntHi++;
    }
    return (cntLo >= 12) ? 1 : (cntHi >= 12 ? 0 : 2); // 0=f32 1=bf16 2=f16
}

static __device__ __forceinline__ float decode_norm(const void* wn, int idx, int fmt) {
    if (fmt == 0) return ((const float*)wn)[idx];
    if (fmt == 1) return bf2f(((const unsigned short*)wn)[idx]);
    return __half2float(((const __half*)wn)[idx]);
}

// ---- kernel 0: x fp32 -> bf16 bits ----
__global__ __launch_bounds__(256)
void xcvt_kernel(const float* __restrict__ x, short* __restrict__ xb)
{
    const int i = (blockIdx.x * 256 + threadIdx.x) * 4;
    f32x4 v = *(const f32x4*)(x + i);
    union { short s[4]; long long q; } p;
    p.s[0] = f2bf(v[0]); p.s[1] = f2bf(v[1]); p.s[2] = f2bf(v[2]); p.s[3] = f2bf(v[3]);
    *(long long*)(xb + i) = p.q;
}

// ---- kernel A: contiguous-burst GEMM. 4096 blocks = 1024 o-octets x 4 k-quarters.
//      Each block reads ONE contiguous 32 KB weight slab (8 rows x 4 KB), all
//      issued up-front, one barrier, consumed fully from LDS. ----
__global__ __launch_bounds__(256, 8)
void gemm_burst(const short* __restrict__ xb,
                const int* __restrict__ wq,
                const void* __restrict__ wn,
                float* __restrict__ part)      // [4][16][8192] f32
{
    const int tid  = threadIdx.x;
    const int w    = tid >> 6;             // wave 0..3
    const int lane = tid & 63;
    const int bid  = blockIdx.x;
    const int ot   = bid >> 2;             // o-octet 0..1023 (8 rows each)
    const int q    = bid & 3;              // k-quarter
    const int o0   = ot * 8;

    const int fmt = sniff_fmt(wn);

    __shared__ int   w_lds[8192];          // 32 KB: [8 rows][256 x 16B units]
    __shared__ float nlds[64];             // this quarter's norms (group-shared)

    if (tid < 64)
        nlds[tid] = decode_norm(wn, (ot >> 1) * NBLOCKS + q * 64 + tid, fmt);

    // ---- staging: wave w stages rows {2w, 2w+1}; per row 4 chunks of 1 KB.
    //      source unit pre-swizzled: lane -> unit c*64 + (lane ^ row)  (row<8)
    {
        const int qbase = q * 1024;        // int32 offset of this quarter
        #pragma unroll
        for (int rr = 0; rr < 2; ++rr) {
            const int r = 2 * w + rr;
            const int* gsrc = wq + (size_t)(o0 + r) * ROW_I32 + qbase;
            #pragma unroll
            for (int c = 0; c < 4; ++c) {
                __builtin_amdgcn_global_load_lds(
                    (GASV*)(gsrc + (c * 64 + (lane ^ r)) * 4),
                    (LASV*)(&w_lds[r * 1024 + c * 256]), 16, 0, 0);
            }
        }
    }
    __syncthreads();   // whole 32 KB slab + nlds ready

    // ---- consume geometry ----
    const int col = lane & 15;             // B col (o-row for col<8) / A row (m)
    const int kg  = lane >> 4;             // 0..3
    const int r   = col & 7;               // LDS row this lane reads
    const float en = (col < 8) ? 1.0f : 0.0f;   // zero-mask for unused B cols
    const short* xrow = xb + (size_t)col * I_TOTAL + kg * 8;

    f32x4 acc = {0.f, 0.f, 0.f, 0.f};

    // wave w owns k-blocks j = w*16 .. w*16+15 of this quarter
    #pragma unroll 4
    for (int jj = 0; jj < 16; ++jj) {
        const int j  = w * 16 + jj;
        const int u  = j * 4 + kg;                 // logical 16B unit in row
        const int s  = u ^ r;                      // swizzled slot
        i32x4 pv = *(const i32x4*)((const char*)w_lds + r * 4096 + s * 16);

        const int kb = q * 64 + j;                 // global k-block
        bf16x8 xa = *(const bf16x8*)(xrow + (size_t)kb * 32);

        const float nf0 = nlds[j];
        const float nf  = nf0 * en;
        const float sc  = nf0 * (2.0f / 15.0f) * en;

        bf16x8 bfrag;
        #pragma unroll
        for (int c = 0; c < 4; ++c) {
            int v = pv[c];
            bfrag[2*c]   = f2bf((float)(v & 15)        * sc - nf);
            bfrag[2*c+1] = f2bf((float)((v >> 4) & 15) * sc - nf);
        }
        acc = __builtin_amdgcn_mfma_f32_16x16x32_bf16(xa, bfrag, acc, 0, 0, 0);
    }

    // ---- cross-wave reduction, red aliased onto w_lds ----
    __syncthreads();                       // all LDS reads done
    float* red = (float*)w_lds;            // 4 KB needed
    *(f32x4*)&red[w * 256 + lane * 4] = acc;
    __syncthreads();

    if (tid < 128) {
        const int m  = tid >> 3;           // batch row 0..15
        const int oc = tid & 7;            // o-row within octet
        const int l  = (m >> 2) * 16 + oc; // source lane (col=oc, hi=m>>2)
        const int rg = m & 3;              // acc register
        float s = 0.f;
        #pragma unroll
        for (int ww = 0; ww < 4; ++ww) s += red[ww * 256 + l * 4 + rg];
        part[(size_t)q * OUT_N + (size_t)m * O_TOTAL + o0 + oc] = s;
    }
}

// ---- kernel B: sum 4 partials + bias ----
__global__ __launch_bounds__(256)
void reduce_k(const float* __restrict__ part, const float* __restrict__ bias,
              float* __restrict__ out)
{
    const int i = (blockIdx.x * 256 + threadIdx.x) * 4;
    f32x4 a = *(const f32x4*)(part + i);
    f32x4 b = *(const f32x4*)(part + OUT_N + i);
    f32x4 c = *(const f32x4*)(part + 2 * OUT_N + i);
    f32x4 d = *(const f32x4*)(part + 3 * OUT_N + i);
    f32x4 bs = *(const f32x4*)(bias + (i & (O_TOTAL - 1)));
    *(f32x4*)(out + i) = a + b + c + d + bs;
}

// ==== fallback: R7 kernel (known 34.1 us) if d_ws too small ====
#define NWAVES  8
#define NSS     32
__global__ __launch_bounds__(512, 6)
void linq4_fb(const short* __restrict__ xb, const int* __restrict__ wq,
              const void* __restrict__ wn, const float* __restrict__ bias,
              float* __restrict__ out)
{
    const int tid  = threadIdx.x;
    const int w    = tid >> 6;
    const int lane = tid & 63;
    const int otile = blockIdx.x;
    const int o0   = otile * 16;
    const int phase = (otile * 7) & (NSS - 1);

    const int fmt = sniff_fmt(wn);

    __shared__ int   w_lds[2][2048];
    __shared__ short x_lds[2][4096];
    __shared__ float nlds[NBLOCKS];
    __shared__ float red[NWAVES][256];

    if (tid < NBLOCKS)
        nlds[tid] = decode_norm(wn, otile * NBLOCKS + tid, fmt);

    const int r_st  = 2 * w + (lane >> 5);
    const int jj    = (lane & 31) ^ (r_st & 7);
    const int* gw_base   = wq + (size_t)(o0 + r_st) * ROW_I32 + jj * 4;
    const short* gx_base = xb + (size_t)r_st * I_TOTAL + jj * 8;

    const int col = lane & 15;
    const int kg  = lane >> 4;
    const int j   = w * 4 + kg;
    const int t   = j ^ (col & 7);
    const int ldsoff = col * 128 + t * 4;
    const int xldoff = col * 256 + t * 8;

    f32x4 acc = {0.f, 0.f, 0.f, 0.f};

    __builtin_amdgcn_global_load_lds((GASV*)(gw_base + phase * 128),
                                     (LASV*)(&w_lds[0][w * 256]), 16, 0, 0);
    __builtin_amdgcn_global_load_lds((GASV*)(gx_base + phase * 256),
                                     (LASV*)(&x_lds[0][w * 512]), 16, 0, 0);
    __syncthreads();

    for (int S = 0; S < NSS; ++S) {
        const int cur = S & 1;
        const int Sp  = (S + phase) & (NSS - 1);
        if (S + 1 < NSS) {
            const int Spn = (S + 1 + phase) & (NSS - 1);
            const int nxt = cur ^ 1;
            __builtin_amdgcn_global_load_lds((GASV*)(gw_base + Spn * 128),
                                             (LASV*)(&w_lds[nxt][w * 256]), 16, 0, 0);
            __builtin_amdgcn_global_load_lds((GASV*)(gx_base + Spn * 256),
                                             (LASV*)(&x_lds[nxt][w * 512]), 16, 0, 0);
        }
        i32x4  pv = *(const i32x4*)(&w_lds[cur][ldsoff]);
        bf16x8 xa = *(const bf16x8*)(&x_lds[cur][xldoff]);
        const float nf = nlds[Sp * 8 + w];
        const float sc = nf * (2.0f / 15.0f);
        bf16x8 bfrag;
        #pragma unroll
        for (int c = 0; c < 4; ++c) {
            int v = pv[c];
            bfrag[2*c]   = f2bf((float)(v & 15)        * sc - nf);
            bfrag[2*c+1] = f2bf((float)((v >> 4) & 15) * sc - nf);
        }
        acc = __builtin_amdgcn_mfma_f32_16x16x32_bf16(xa, bfrag, acc, 0, 0, 0);
        __syncthreads();
    }

    *(f32x4*)&red[w][lane * 4] = acc;
    __syncthreads();

    if (tid < 256) {
        float s = 0.f;
        #pragma unroll
        for (int qq = 0; qq < NWAVES; ++qq) s += red[qq][tid];
        const int l = tid >> 2;
        const int rr = tid & 3;
        const int m  = ((l >> 4) << 2) + rr;
        const int oc = o0 + (l & 15);
        out[(size_t)m * O_TOTAL + oc] = s + bias[oc];
    }
}

extern "C" void kernel_launch(void* const* d_in, const int* in_sizes, int n_in,
                              void* d_out, int out_size, void* d_ws, size_t ws_size,
                              hipStream_t stream) {
    const float* x    = (const float*)d_in[0];
    const int*   wq   = (const int*)d_in[1];
    const void*  wn   = (const void*)d_in[2];
    const float* bias = (const float*)d_in[3];
    float* out = (float*)d_out;

    short* xb = (short*)d_ws;                              // 256 KB
    const size_t xb_bytes   = (size_t)16 * I_TOTAL * 2;
    const size_t part_bytes = (size_t)4 * OUT_N * 4;       // 2 MB

    hipLaunchKernelGGL(xcvt_kernel, dim3(16 * I_TOTAL / 4 / 256), dim3(256), 0, stream, x, xb);

    if (ws_size >= xb_bytes + part_bytes) {
        float* part = (float*)((char*)d_ws + xb_bytes);
        hipLaunchKernelGGL(gemm_burst, dim3(1024 * 4), dim3(256), 0, stream,
                           (const short*)xb, wq, wn, part);
        hipLaunchKernelGGL(reduce_k, dim3(OUT_N / 4 / 256), dim3(256), 0, stream,
                           (const float*)part, bias, out);
    } else {
        hipLaunchKernelGGL(linq4_fb, dim3(O_TOTAL / 16), dim3(512), 0, stream,
                           (const short*)xb, wq, wn, bias, out);
    }
}